// Round 11
// baseline (2630.840 us; speedup 1.0000x reference)
//
#include <hip/hip_runtime.h>
#include <hip/hip_bf16.h>
#include <math.h>

// Problem constants
#define BATCH   256
#define T_STEPS 4096
#define IN_DIM  28
#define HID     128
#define GATES   512   // 4*HID
#define OUT_DIM 10

#define HPAD    16                    // ushort pad: buf/par regions hit different banks
#define PARSTRIDE (HID + HPAD)        // ushorts between par=0 and par=1 regions
#define BUFSTRIDE (2 * PARSTRIDE)     // ushorts between buf 0 and buf 1

typedef short bf16x8 __attribute__((ext_vector_type(8)));  // 8 bf16 in 4 VGPRs
typedef float f32x4  __attribute__((ext_vector_type(4)));

#define SGB __builtin_amdgcn_sched_group_barrier
// LLVM SchedGroupMask: VALU=0x2, MFMA=0x8, DS_READ=0x100

#define LOG2E  1.44269504f
#define LOG2E2 2.88539008f

__device__ __forceinline__ float frcp_fast(float x) {
    return __builtin_amdgcn_rcpf(x);
}

__device__ __forceinline__ unsigned short f2bf(float f) {
    __hip_bfloat16 h = __float2bfloat16(f);   // RNE
    return __builtin_bit_cast(unsigned short, h);
}
__device__ __forceinline__ float bf2f(unsigned short u) {
    return __bfloat162float(__builtin_bit_cast(__hip_bfloat16, u));
}

__device__ __forceinline__ float sigm(float x) {
    float e = __builtin_exp2f(x * -LOG2E);
    return frcp_fast(1.0f + e);
}
__device__ __forceinline__ float tanh_fast(float x) {
    // tanh(x) = 1 - 2/(1+e^{2x}) — exact at both infinities
    float e = __builtin_exp2f(x * LOG2E2);
    return 1.0f - 2.0f * frcp_fast(1.0f + e);
}

// ---------------------------------------------------------------------------
// Kernel 1: input projection for batch element 255, UNIT-MAJOR output:
// gx2[t, u, gt] = dot(x255[t,:], w_ih[gt*128+u,:]) + b_ih[..] + b_hh[..]
// ---------------------------------------------------------------------------
__global__ __launch_bounds__(GATES) void k_inproj(const float* __restrict__ x255,
                                                  const float* __restrict__ w_ih,
                                                  const float* __restrict__ b_ih,
                                                  const float* __restrict__ b_hh,
                                                  float* __restrict__ gx2) {
    const int t = blockIdx.x;
    const int g = threadIdx.x;          // gate row 0..511 (i|f|g|o blocks of 128)
    const int unit = g & (HID - 1);
    const int quad = g >> 7;
    __shared__ float xs[IN_DIM];
    if (g < IN_DIM) xs[g] = x255[t * IN_DIM + g];
    __syncthreads();
    float acc = b_ih[g] + b_hh[g];
    const float* __restrict__ wr = w_ih + g * IN_DIM;
#pragma unroll
    for (int k = 0; k < IN_DIM; ++k) acc += wr[k] * xs[k];
    gx2[t * GATES + unit * 4 + quad] = acc;
}

// ---------------------------------------------------------------------------
// Kernel 2 (main): MFMA LSTM scan — 256 threads = 4 waves, ONE WAVE PER SIMD.
//
// R11 rationale (R5-R10 counter decomposition): step ~1350cy = 512cy MFMA
// issue (hard floor: 32 MFMA/SIMD x 16cy) + ~230cy pure VALU + ~600cy STALL.
// With 2 barrier-locked waves/SIMD the waves run in-phase: they contend for
// the MFMA pipe during the burst and idle it during the epilogue. With ONE
// wave/SIMD owning 32 units (2 column-tiles), total MFMA/SIMD is unchanged
// (same 512cy floor) but in-order issue lets OUR source interleave thread
// the (doubled) epilogue VALU into the 16cy gaps between MFMA issues —
// deterministically, no co-wave arbitration.
//
// Layout per wave w (0..3): units [32w, 32w+32); ct=0 -> cols=units
// 32w+cidx, ct=1 -> 32w+16+cidx. Operand-swapped MFMA (R7-verified):
// A = h (even rows h_hi, odd h_lo), B = W_hh col=unit; lane holds
// reg0=hi-part, reg1=lo-part of its own unit -> pre = a[0]+a[1]+gx.
// Phase A: f/i chains (4 chains, kt round-robin, dep dist 64cy).
// Phase B: g/o chains with f/i activations + fv*c threaded between rounds.
// Tail: g-act, c, tanh(c), o-act, h, cvt, distributed writes (q0/q1/q2).
// ---------------------------------------------------------------------------
__global__ __attribute__((amdgpu_flat_work_group_size(256, 256),
                          amdgpu_waves_per_eu(1, 1)))
void k_scan_mfma(const float* __restrict__ gx2,
                 const float* __restrict__ w_hh,
                 float* __restrict__ hs) {
    const int tid   = threadIdx.x;      // 0..255
    const int w     = tid >> 6;         // wave 0..3
    const int l     = tid & 63;         // lane 0..63
    const int q     = l >> 4;           // k-group / D row-group 0..3
    const int cidx  = l & 15;           // D column = unit within tile
    const int par   = cidx & 1;         // A-row parity: 0 -> h_hi, 1 -> h_lo
    const int ubase = w * 32;
    const int uA    = ubase + cidx;          // ct=0 unit
    const int uB    = ubase + 16 + cidx;     // ct=1 unit

    __shared__ __align__(16) unsigned short hb[2 * BUFSTRIDE];

    // ---- one-time: B-frags wb_[ct][gate][kt] (128 regs/wave) ----
    // lane l holds B[k = kt*32 + q*8 + j][col = cidx] = W_hh[gt*128+u][k]
    bf16x8 wb_[2][4][4];
#pragma unroll
    for (int ct = 0; ct < 2; ++ct) {
#pragma unroll
        for (int gt = 0; gt < 4; ++gt) {
            const int row = gt * HID + ubase + ct * 16 + cidx;
            const float* __restrict__ wr = w_hh + row * HID;
#pragma unroll
            for (int kt = 0; kt < 4; ++kt) {
                const int k0 = kt * 32 + q * 8;
                bf16x8 v;
#pragma unroll
                for (int j = 0; j < 8; ++j) v[j] = (short)f2bf(wr[k0 + j]);
                wb_[ct][gt][kt] = v;
            }
        }
    }

    // zero both buffers (both parities); 256 threads cover HID=128
    if (tid < HID) {
        hb[0 * BUFSTRIDE + 0 * PARSTRIDE + tid] = 0;
        hb[0 * BUFSTRIDE + 1 * PARSTRIDE + tid] = 0;
        hb[1 * BUFSTRIDE + 0 * PARSTRIDE + tid] = 0;
        hb[1 * BUFSTRIDE + 1 * PARSTRIDE + tid] = 0;
    }
    float cA = 0.0f, cB = 0.0f;          // cell states (replicated across q)
    const unsigned short* __restrict__ hq = &hb[par * PARSTRIDE + q * 8]; // A-frag base
    unsigned short* __restrict__ wptA = &hb[uA];
    unsigned short* __restrict__ wptB = &hb[uB];
    const f32x4 ZQ = {0.f, 0.f, 0.f, 0.f};   // persistent zero C-operand

    float4 gnA = *reinterpret_cast<const float4*>(gx2 + uA * 4);  // t=0
    float4 gnB = *reinterpret_cast<const float4*>(gx2 + uB * 4);
    __syncthreads();

// gate type indices: i=0, f=1, g=2, o=3
#define MF(A, CT, G, K, C_) __builtin_amdgcn_mfma_f32_16x16x32_bf16((A), wb_[CT][G][K], (C_), 0, 0, 0)

#define LSTM_STEP(T, RB, WB)                                                   \
    {                                                                          \
        float4 gA = gnA, gB = gnB;                                             \
        if ((T) + 1 < T_STEPS) {                                               \
            gnA = *reinterpret_cast<const float4*>(gx2 + ((T) + 1) * GATES + uA * 4); \
            gnB = *reinterpret_cast<const float4*>(gx2 + ((T) + 1) * GATES + uB * 4); \
        }                                                                      \
        bf16x8 af0 = *reinterpret_cast<const bf16x8*>(hq + (RB) * BUFSTRIDE + 0 * 32); \
        bf16x8 af1 = *reinterpret_cast<const bf16x8*>(hq + (RB) * BUFSTRIDE + 1 * 32); \
        bf16x8 af2 = *reinterpret_cast<const bf16x8*>(hq + (RB) * BUFSTRIDE + 2 * 32); \
        bf16x8 af3 = *reinterpret_cast<const bf16x8*>(hq + (RB) * BUFSTRIDE + 3 * 32); \
        /* Phase A: f,i chains for both ct (4 chains, kt round-robin) */       \
        f32x4 fA = MF(af0, 0, 1, 0, ZQ);                                       \
        f32x4 fB = MF(af0, 1, 1, 0, ZQ);                                       \
        f32x4 iA = MF(af0, 0, 0, 0, ZQ);                                       \
        f32x4 iB = MF(af0, 1, 0, 0, ZQ);                                       \
        fA = MF(af1, 0, 1, 1, fA); fB = MF(af1, 1, 1, 1, fB);                  \
        iA = MF(af1, 0, 0, 1, iA); iB = MF(af1, 1, 0, 1, iB);                  \
        fA = MF(af2, 0, 1, 2, fA); fB = MF(af2, 1, 1, 2, fB);                  \
        iA = MF(af2, 0, 0, 2, iA); iB = MF(af2, 1, 0, 2, iB);                  \
        fA = MF(af3, 0, 1, 3, fA); fB = MF(af3, 1, 1, 3, fB);                  \
        iA = MF(af3, 0, 0, 3, iA); iB = MF(af3, 1, 0, 3, iB);                  \
        /* Phase B: g,o chains; f/i activations threaded between kt rounds */  \
        f32x4 gAc = MF(af0, 0, 2, 0, ZQ);                                      \
        f32x4 gBc = MF(af0, 1, 2, 0, ZQ);                                      \
        f32x4 oAc = MF(af0, 0, 3, 0, ZQ);                                      \
        f32x4 oBc = MF(af0, 1, 3, 0, ZQ);                                      \
        float p1A = (fA[0] + fA[1]) + gA.y;                                    \
        float efA = __builtin_exp2f(p1A * -LOG2E);                             \
        float fvA = frcp_fast(1.0f + efA);                                     \
        float fcA = fvA * cA;                                                  \
        gAc = MF(af1, 0, 2, 1, gAc); gBc = MF(af1, 1, 2, 1, gBc);              \
        float p1B = (fB[0] + fB[1]) + gB.y;                                    \
        float efB = __builtin_exp2f(p1B * -LOG2E);                             \
        float fvB = frcp_fast(1.0f + efB);                                     \
        float fcB = fvB * cB;                                                  \
        oAc = MF(af1, 0, 3, 1, oAc); oBc = MF(af1, 1, 3, 1, oBc);              \
        float p0A = (iA[0] + iA[1]) + gA.x;                                    \
        float eiA = __builtin_exp2f(p0A * -LOG2E);                             \
        float ivA = frcp_fast(1.0f + eiA);                                     \
        gAc = MF(af2, 0, 2, 2, gAc); gBc = MF(af2, 1, 2, 2, gBc);              \
        float p0B = (iB[0] + iB[1]) + gB.x;                                    \
        float eiB = __builtin_exp2f(p0B * -LOG2E);                             \
        float ivB = frcp_fast(1.0f + eiB);                                     \
        oAc = MF(af2, 0, 3, 2, oAc); oBc = MF(af2, 1, 3, 2, oBc);              \
        gAc = MF(af3, 0, 2, 3, gAc); gBc = MF(af3, 1, 2, 3, gBc);              \
        oAc = MF(af3, 0, 3, 3, oAc); oBc = MF(af3, 1, 3, 3, oBc);              \
        /* tail: g-act, c, tanh(c), o-act, h for both units */                 \
        float p2A = (gAc[0] + gAc[1]) + gA.z;                                  \
        float egA = __builtin_exp2f(p2A * LOG2E2);                             \
        float gvA = __builtin_fmaf(-2.0f, frcp_fast(1.0f + egA), 1.0f);        \
        float cnA = __builtin_fmaf(ivA, gvA, fcA);                             \
        cA = cnA;                                                              \
        float ecA = __builtin_exp2f(cnA * LOG2E2);                             \
        float thA = __builtin_fmaf(-2.0f, frcp_fast(1.0f + ecA), 1.0f);        \
        float p2B = (gBc[0] + gBc[1]) + gB.z;                                  \
        float egB = __builtin_exp2f(p2B * LOG2E2);                             \
        float gvB = __builtin_fmaf(-2.0f, frcp_fast(1.0f + egB), 1.0f);        \
        float cnB = __builtin_fmaf(ivB, gvB, fcB);                             \
        cB = cnB;                                                              \
        float ecB = __builtin_exp2f(cnB * LOG2E2);                             \
        float thB = __builtin_fmaf(-2.0f, frcp_fast(1.0f + ecB), 1.0f);        \
        float p3A = (oAc[0] + oAc[1]) + gA.w;                                  \
        float eoA = __builtin_exp2f(p3A * -LOG2E);                             \
        float ovA = frcp_fast(1.0f + eoA);                                     \
        float hA = ovA * thA;                                                  \
        float p3B = (oBc[0] + oBc[1]) + gB.w;                                  \
        float eoB = __builtin_exp2f(p3B * -LOG2E);                             \
        float ovB = frcp_fast(1.0f + eoB);                                     \
        float hB = ovB * thB;                                                  \
        unsigned short hiA = f2bf(hA);                                         \
        unsigned short hiB = f2bf(hB);                                         \
        if (q == 0) {                                                          \
            wptA[(WB) * BUFSTRIDE] = hiA;                                      \
            wptB[(WB) * BUFSTRIDE] = hiB;                                      \
        }                                                                      \
        if (q == 1) {                                                          \
            wptA[(WB) * BUFSTRIDE + PARSTRIDE] = f2bf(hA - bf2f(hiA));         \
            wptB[(WB) * BUFSTRIDE + PARSTRIDE] = f2bf(hB - bf2f(hiB));         \
        }                                                                      \
        if (q == 2) {                                                          \
            hs[(T) * HID + uA] = hA;                                           \
            hs[(T) * HID + uB] = hB;                                           \
        }                                                                      \
        /* pins: 4 ds_reads, phase-A burst, then B rounds with VALU slots */   \
        SGB(0x100, 4, 0);                                                      \
        SGB(0x008, 16, 0);                                                     \
        SGB(0x008, 4, 0); SGB(0x002, 4, 0);                                    \
        SGB(0x008, 2, 0); SGB(0x002, 4, 0);                                    \
        SGB(0x008, 2, 0); SGB(0x002, 3, 0);                                    \
        SGB(0x008, 2, 0); SGB(0x002, 3, 0);                                    \
        SGB(0x008, 2, 0); SGB(0x002, 3, 0);                                    \
        SGB(0x008, 4, 0);                                                      \
        __syncthreads();                                                       \
    }

    for (int t = 0; t < T_STEPS; t += 2) {
        LSTM_STEP(t, 1, 0);       // even step: read buf1 (zeroed at t=0), write buf0
        LSTM_STEP(t + 1, 0, 1);   // odd step: read buf0, write buf1
    }
#undef LSTM_STEP
#undef MF
}

// ---------------------------------------------------------------------------
// Fallback scan (fused input projection, f32 VALU) — only if d_ws too small.
// ---------------------------------------------------------------------------
__global__ __launch_bounds__(GATES) void k_scan_valu(const float* __restrict__ w_hh,
                                                     float* __restrict__ hs,
                                                     const float* __restrict__ x255,
                                                     const float* __restrict__ w_ih,
                                                     const float* __restrict__ b_ih,
                                                     const float* __restrict__ b_hh) {
    const int g    = threadIdx.x;
    const int quad = g >> 7;

    __shared__ float h_sh[HID];
    __shared__ float act_sh[GATES];
    __shared__ float xs[IN_DIM];

    float4 wv[HID / 4];
    const float4* __restrict__ wrow = reinterpret_cast<const float4*>(w_hh + g * HID);
#pragma unroll
    for (int k = 0; k < HID / 4; ++k) wv[k] = wrow[k];

    float bsum = b_ih[g] + b_hh[g];
    float wih[IN_DIM];
#pragma unroll
    for (int k = 0; k < IN_DIM; ++k) wih[k] = w_ih[g * IN_DIM + k];

    if (g < HID) h_sh[g] = 0.0f;
    float c = 0.0f;
    __syncthreads();

    for (int t = 0; t < T_STEPS; ++t) {
        __syncthreads();
        if (g < IN_DIM) xs[g] = x255[t * IN_DIM + g];
        __syncthreads();
        float a0 = bsum, a1 = 0.0f, a2 = 0.0f, a3 = 0.0f;
#pragma unroll
        for (int k = 0; k < IN_DIM; ++k) a0 += wih[k] * xs[k];

        const float4* __restrict__ h4 = reinterpret_cast<const float4*>(h_sh);
#pragma unroll
        for (int k = 0; k < HID / 4; ++k) {
            float4 hv = h4[k];
            a0 += wv[k].x * hv.x;
            a1 += wv[k].y * hv.y;
            a2 += wv[k].z * hv.z;
            a3 += wv[k].w * hv.w;
        }
        float pre = (a0 + a1) + (a2 + a3);
        float a = (quad == 2) ? tanh_fast(pre) : sigm(pre);
        act_sh[g] = a;
        __syncthreads();

        if (g < HID) {
            float iv = act_sh[g];
            float fv = act_sh[HID + g];
            float gv = act_sh[2 * HID + g];
            float ov = act_sh[3 * HID + g];
            c = fv * c + iv * gv;
            float h = ov * tanh_fast(c);
            h_sh[g] = h;
            hs[t * HID + g] = h;
        }
        __syncthreads();
    }
}

// ---------------------------------------------------------------------------
// Kernel 3: final FC — out[t, o] = dot(hs[t, :], w_fc[o, :]) + b_fc[o]
// ---------------------------------------------------------------------------
__global__ __launch_bounds__(256) void k_fc(const float* __restrict__ hs,
                                            const float* __restrict__ w_fc,
                                            const float* __restrict__ b_fc,
                                            float* __restrict__ out) {
    const int idx = blockIdx.x * blockDim.x + threadIdx.x;
    if (idx >= T_STEPS * OUT_DIM) return;
    const int t = idx / OUT_DIM;
    const int o = idx - t * OUT_DIM;
    const float* __restrict__ hrow = hs + t * HID;
    const float* __restrict__ wrow = w_fc + o * HID;
    float acc = b_fc[o];
#pragma unroll 8
    for (int k = 0; k < HID; ++k) acc += hrow[k] * wrow[k];
    out[idx] = acc;
}

// ---------------------------------------------------------------------------
extern "C" void kernel_launch(void* const* d_in, const int* in_sizes, int n_in,
                              void* d_out, int out_size, void* d_ws, size_t ws_size,
                              hipStream_t stream) {
    const float* x    = (const float*)d_in[0];  // [B, T, I]
    const float* w_ih = (const float*)d_in[1];  // [4H, I]
    const float* w_hh = (const float*)d_in[2];  // [4H, H]
    const float* b_ih = (const float*)d_in[3];  // [4H]
    const float* b_hh = (const float*)d_in[4];  // [4H]
    const float* w_fc = (const float*)d_in[5];  // [OUT, H]
    const float* b_fc = (const float*)d_in[6];  // [OUT]
    float* out = (float*)d_out;                 // [T, OUT]

    // Only batch element B-1 is observable in the reference output.
    const float* x255 = x + (size_t)(BATCH - 1) * T_STEPS * IN_DIM;

    float* hs = (float*)d_ws;                                  // 4096*128 f32 = 2 MB
    float* gx2 = hs + (size_t)T_STEPS * HID;                   // 4096*512 f32 = 8 MB (unit-major)
    const size_t need_full = (size_t)(T_STEPS * HID + T_STEPS * GATES) * sizeof(float);

    if (ws_size >= need_full) {
        k_inproj<<<T_STEPS, GATES, 0, stream>>>(x255, w_ih, b_ih, b_hh, gx2);
        k_scan_mfma<<<1, 256, 0, stream>>>(gx2, w_hh, hs);
    } else {
        k_scan_valu<<<1, GATES, 0, stream>>>(w_hh, hs, x255, w_ih, b_ih, b_hh);
    }

    const int n = T_STEPS * OUT_DIM;
    k_fc<<<(n + 255) / 256, 256, 0, stream>>>(hs, w_fc, b_fc, out);
}

// Round 12
// 2305.527 us; speedup vs baseline: 1.1411x; 1.1411x over previous
//
#include <hip/hip_runtime.h>
#include <hip/hip_bf16.h>
#include <math.h>

// Problem constants
#define BATCH   256
#define T_STEPS 4096
#define IN_DIM  28
#define HID     128
#define GATES   512   // 4*HID
#define OUT_DIM 10

#define HPAD    16                    // ushort pad: buf/par regions hit different banks
#define PARSTRIDE (HID + HPAD)        // ushorts between par=0 and par=1 regions
#define BUFSTRIDE (2 * PARSTRIDE)     // ushorts between buf 0 and buf 1

typedef short bf16x8 __attribute__((ext_vector_type(8)));  // 8 bf16 in 4 VGPRs
typedef float f32x4  __attribute__((ext_vector_type(4)));

#define SGB __builtin_amdgcn_sched_group_barrier
// LLVM SchedGroupMask: VALU=0x2, MFMA=0x8, DS_READ=0x100

__device__ __forceinline__ float frcp_fast(float x) {
    return __builtin_amdgcn_rcpf(x);
}

__device__ __forceinline__ unsigned short f2bf(float f) {
    __hip_bfloat16 h = __float2bfloat16(f);   // RNE
    return __builtin_bit_cast(unsigned short, h);
}
__device__ __forceinline__ float bf2f(unsigned short u) {
    return __bfloat162float(__builtin_bit_cast(__hip_bfloat16, u));
}

__device__ __forceinline__ float sigm(float x) {
    float e = __builtin_exp2f(x * -1.44269504f);
    return frcp_fast(1.0f + e);
}
__device__ __forceinline__ float tanh_fast(float x) {
    // tanh(x) = 1 - 2/(1+e^{2x}) — exact at both infinities
    float e = __builtin_exp2f(x * 2.88539008f);
    return 1.0f - 2.0f * frcp_fast(1.0f + e);
}

// ---------------------------------------------------------------------------
// Kernel 1: input projection for batch element 255, UNIT-MAJOR output:
// gx2[t, u, gt] = dot(x255[t,:], w_ih[gt*128+u,:]) + b_ih[..] + b_hh[..]
// ---------------------------------------------------------------------------
__global__ __launch_bounds__(GATES) void k_inproj(const float* __restrict__ x255,
                                                  const float* __restrict__ w_ih,
                                                  const float* __restrict__ b_ih,
                                                  const float* __restrict__ b_hh,
                                                  float* __restrict__ gx2) {
    const int t = blockIdx.x;
    const int g = threadIdx.x;          // gate row 0..511 (i|f|g|o blocks of 128)
    const int unit = g & (HID - 1);
    const int quad = g >> 7;
    __shared__ float xs[IN_DIM];
    if (g < IN_DIM) xs[g] = x255[t * IN_DIM + g];
    __syncthreads();
    float acc = b_ih[g] + b_hh[g];
    const float* __restrict__ wr = w_ih + g * IN_DIM;
#pragma unroll
    for (int k = 0; k < IN_DIM; ++k) acc += wr[k] * xs[k];
    gx2[t * GATES + unit * 4 + quad] = acc;
}

// ---------------------------------------------------------------------------
// Kernel 2 (main): MFMA LSTM scan — 512 threads (8 waves), unit-major,
// operand-swapped (R7-verified): A = h (EVEN rows h_hi, ODD rows h_lo),
// B = W_hh (col n = unit). Lane: col cidx = its unit; reg0 = hi-part,
// reg1 = lo-part -> pre = a[0]+a[1]+gx, static regs.
//
// === R12: BYTE-LEVEL REVERT TO R9 (best measured: 2308 us) ===
// Session scoreboard: R5 2375, R6 2920, R7 2391, R8 2348, R9 2308 (best),
// R10 2439 (dual-acc regressed), R11 2631 (1-wave/SIMD regressed; the
// co-resident wave HIDES latency, it doesn't contend).
// Structural floor: 128 MFMA/step / 4 SIMD x 16cy = 512cy issue (M-dim
// redundancy is structural: B can't vary with M, hi/lo fills 2/16 rows;
// MX-fp8 K=128 at 2x rate needs 2x MFMAs for precision = no gain) +
// ~830cy serial recurrence latency (ds_read -> dep-MFMA chain -> exp chains
// -> c -> tanh -> cvt -> ds_write -> barrier) that 6 scheduling attacks
// could not compress below this kernel's level.
// ---------------------------------------------------------------------------
__global__ __attribute__((amdgpu_flat_work_group_size(512, 512),
                          amdgpu_waves_per_eu(2, 2)))
void k_scan_mfma(const float* __restrict__ gx2,
                 const float* __restrict__ w_hh,
                 float* __restrict__ hs) {
    const int tid   = threadIdx.x;
    const int w     = tid >> 6;         // wave 0..7
    const int l     = tid & 63;         // lane 0..63
    const int q     = l >> 4;           // k-group / D row-group 0..3
    const int cidx  = l & 15;           // D column = unit within wave
    const int par   = cidx & 1;         // A-row parity: 0 -> h_hi, 1 -> h_lo
    const int ubase = w * 16;
    const int u     = ubase + cidx;     // unit this lane finalizes

    __shared__ __align__(16) unsigned short hb[2 * BUFSTRIDE];

    // ---- one-time: B-frags wb_[gate_type][kt] (64 VGPRs) ----
    // lane l holds B[k = kt*32 + q*8 + j][col = cidx] = W_hh[gt*128+u][k]
    bf16x8 wb_[4][4];
#pragma unroll
    for (int gt = 0; gt < 4; ++gt) {
        const int row = gt * HID + u;
        const float* __restrict__ wr = w_hh + row * HID;
#pragma unroll
        for (int kt = 0; kt < 4; ++kt) {
            const int k0 = kt * 32 + q * 8;
            bf16x8 v;
#pragma unroll
            for (int j = 0; j < 8; ++j) v[j] = (short)f2bf(wr[k0 + j]);
            wb_[gt][kt] = v;
        }
    }

    // zero both buffers (both parities)
    if (tid < HID) {
        hb[0 * BUFSTRIDE + 0 * PARSTRIDE + tid] = 0;
        hb[0 * BUFSTRIDE + 1 * PARSTRIDE + tid] = 0;
        hb[1 * BUFSTRIDE + 0 * PARSTRIDE + tid] = 0;
        hb[1 * BUFSTRIDE + 1 * PARSTRIDE + tid] = 0;
    }
    float c = 0.0f;                     // cell state (4x replicated per unit)
    const unsigned short* __restrict__ hq = &hb[par * PARSTRIDE + q * 8]; // A-frag base
    unsigned short* __restrict__ wpt = &hb[u];                            // writer base
    const f32x4 ZQ = {0.f, 0.f, 0.f, 0.f};   // persistent zero C-operand

    float4 gnext = *reinterpret_cast<const float4*>(gx2 + u * 4);  // t=0
    __syncthreads();

#define MF(A, G, K, C_) __builtin_amdgcn_mfma_f32_16x16x32_bf16((A), wb_[G][K], (C_), 0, 0, 0)

#define LSTM_STEP(T, RB, WB)                                                   \
    {                                                                          \
        float4 gcur = gnext;                                                   \
        if ((T) + 1 < T_STEPS)                                                 \
            gnext = *reinterpret_cast<const float4*>(gx2 + ((T) + 1) * GATES + u * 4); \
        bf16x8 af0 = *reinterpret_cast<const bf16x8*>(hq + (RB) * BUFSTRIDE + 0 * 32); \
        bf16x8 af1 = *reinterpret_cast<const bf16x8*>(hq + (RB) * BUFSTRIDE + 1 * 32); \
        bf16x8 af2 = *reinterpret_cast<const bf16x8*>(hq + (RB) * BUFSTRIDE + 2 * 32); \
        bf16x8 af3 = *reinterpret_cast<const bf16x8*>(hq + (RB) * BUFSTRIDE + 3 * 32); \
        /* g-gate chain first (its tanh is the longest activation) */          \
        f32x4 a2 = MF(af0, 2, 0, ZQ);                                          \
        a2 = MF(af1, 2, 1, a2);                                                \
        a2 = MF(af2, 2, 2, a2);                                                \
        a2 = MF(af3, 2, 3, a2);                                                \
        /* o-chain, g-activation threaded between */                           \
        f32x4 a3 = MF(af0, 3, 0, ZQ);                                          \
        float p2 = (a2[0] + a2[1]) + gcur.z;                                   \
        a3 = MF(af1, 3, 1, a3);                                                \
        float eg = __builtin_exp2f(p2 * 2.88539008f);                          \
        a3 = MF(af2, 3, 2, a3);                                                \
        float dg = 1.0f + eg;                                                  \
        a3 = MF(af3, 3, 3, a3);                                                \
        float gv = __builtin_fmaf(-2.0f, frcp_fast(dg), 1.0f);                 \
        /* i-chain, o-activation threaded between */                           \
        f32x4 a0 = MF(af0, 0, 0, ZQ);                                          \
        float p3 = (a3[0] + a3[1]) + gcur.w;                                   \
        a0 = MF(af1, 0, 1, a0);                                                \
        float eo = __builtin_exp2f(p3 * -1.44269504f);                         \
        a0 = MF(af2, 0, 2, a0);                                                \
        float dosum = 1.0f + eo;                                               \
        a0 = MF(af3, 0, 3, a0);                                                \
        float ov = frcp_fast(dosum);                                           \
        /* f-chain, i-activation threaded between */                           \
        f32x4 a1 = MF(af0, 1, 0, ZQ);                                          \
        float p0 = (a0[0] + a0[1]) + gcur.x;                                   \
        a1 = MF(af1, 1, 1, a1);                                                \
        float ei = __builtin_exp2f(p0 * -1.44269504f);                         \
        a1 = MF(af2, 1, 2, a1);                                                \
        float di = 1.0f + ei;                                                  \
        a1 = MF(af3, 1, 3, a1);                                                \
        float iv = frcp_fast(di);                                              \
        /* tail */                                                             \
        float p1 = (a1[0] + a1[1]) + gcur.y;                                   \
        float ef = __builtin_exp2f(p1 * -1.44269504f);                         \
        float fv = frcp_fast(1.0f + ef);                                       \
        float ig = iv * gv;                                                    \
        c = __builtin_fmaf(fv, c, ig);                                         \
        float ec = __builtin_exp2f(c * 2.88539008f);                           \
        float th = __builtin_fmaf(-2.0f, frcp_fast(1.0f + ec), 1.0f);          \
        float h = ov * th;                                                     \
        unsigned short hi = f2bf(h);                                           \
        if (q == 0) wpt[(WB) * BUFSTRIDE] = hi;                                \
        if (q == 1) wpt[(WB) * BUFSTRIDE + PARSTRIDE] = f2bf(h - bf2f(hi));    \
        if (q == 2) hs[(T) * HID + u] = h;                                     \
        /* pin the interleave: reads, g-burst, then MFMA/VALU alternation */   \
        SGB(0x100, 4, 0);                                                      \
        SGB(0x008, 4, 0);                                                      \
        SGB(0x008, 1, 0); SGB(0x002, 2, 0);                                    \
        SGB(0x008, 1, 0); SGB(0x002, 2, 0);                                    \
        SGB(0x008, 1, 0); SGB(0x002, 2, 0);                                    \
        SGB(0x008, 1, 0); SGB(0x002, 2, 0);                                    \
        SGB(0x008, 1, 0); SGB(0x002, 2, 0);                                    \
        SGB(0x008, 1, 0); SGB(0x002, 2, 0);                                    \
        SGB(0x008, 1, 0); SGB(0x002, 2, 0);                                    \
        SGB(0x008, 1, 0); SGB(0x002, 2, 0);                                    \
        SGB(0x008, 1, 0); SGB(0x002, 2, 0);                                    \
        SGB(0x008, 1, 0); SGB(0x002, 2, 0);                                    \
        SGB(0x008, 1, 0); SGB(0x002, 2, 0);                                    \
        SGB(0x008, 1, 0); SGB(0x002, 2, 0);                                    \
        __syncthreads();                                                       \
    }

    for (int t = 0; t < T_STEPS; t += 2) {
        LSTM_STEP(t, 1, 0);       // even step: read buf1 (zeroed at t=0), write buf0
        LSTM_STEP(t + 1, 0, 1);   // odd step: read buf0, write buf1
    }
#undef LSTM_STEP
#undef MF
}

// ---------------------------------------------------------------------------
// Fallback scan (fused input projection, f32 VALU) — only if d_ws too small.
// ---------------------------------------------------------------------------
__global__ __launch_bounds__(GATES) void k_scan_valu(const float* __restrict__ w_hh,
                                                     float* __restrict__ hs,
                                                     const float* __restrict__ x255,
                                                     const float* __restrict__ w_ih,
                                                     const float* __restrict__ b_ih,
                                                     const float* __restrict__ b_hh) {
    const int g    = threadIdx.x;
    const int quad = g >> 7;

    __shared__ float h_sh[HID];
    __shared__ float act_sh[GATES];
    __shared__ float xs[IN_DIM];

    float4 wv[HID / 4];
    const float4* __restrict__ wrow = reinterpret_cast<const float4*>(w_hh + g * HID);
#pragma unroll
    for (int k = 0; k < HID / 4; ++k) wv[k] = wrow[k];

    float bsum = b_ih[g] + b_hh[g];
    float wih[IN_DIM];
#pragma unroll
    for (int k = 0; k < IN_DIM; ++k) wih[k] = w_ih[g * IN_DIM + k];

    if (g < HID) h_sh[g] = 0.0f;
    float c = 0.0f;
    __syncthreads();

    for (int t = 0; t < T_STEPS; ++t) {
        __syncthreads();
        if (g < IN_DIM) xs[g] = x255[t * IN_DIM + g];
        __syncthreads();
        float a0 = bsum, a1 = 0.0f, a2 = 0.0f, a3 = 0.0f;
#pragma unroll
        for (int k = 0; k < IN_DIM; ++k) a0 += wih[k] * xs[k];

        const float4* __restrict__ h4 = reinterpret_cast<const float4*>(h_sh);
#pragma unroll
        for (int k = 0; k < HID / 4; ++k) {
            float4 hv = h4[k];
            a0 += wv[k].x * hv.x;
            a1 += wv[k].y * hv.y;
            a2 += wv[k].z * hv.z;
            a3 += wv[k].w * hv.w;
        }
        float pre = (a0 + a1) + (a2 + a3);
        float a = (quad == 2) ? tanh_fast(pre) : sigm(pre);
        act_sh[g] = a;
        __syncthreads();

        if (g < HID) {
            float iv = act_sh[g];
            float fv = act_sh[HID + g];
            float gv = act_sh[2 * HID + g];
            float ov = act_sh[3 * HID + g];
            c = fv * c + iv * gv;
            float h = ov * tanh_fast(c);
            h_sh[g] = h;
            hs[t * HID + g] = h;
        }
        __syncthreads();
    }
}

// ---------------------------------------------------------------------------
// Kernel 3: final FC — out[t, o] = dot(hs[t, :], w_fc[o, :]) + b_fc[o]
// ---------------------------------------------------------------------------
__global__ __launch_bounds__(256) void k_fc(const float* __restrict__ hs,
                                            const float* __restrict__ w_fc,
                                            const float* __restrict__ b_fc,
                                            float* __restrict__ out) {
    const int idx = blockIdx.x * blockDim.x + threadIdx.x;
    if (idx >= T_STEPS * OUT_DIM) return;
    const int t = idx / OUT_DIM;
    const int o = idx - t * OUT_DIM;
    const float* __restrict__ hrow = hs + t * HID;
    const float* __restrict__ wrow = w_fc + o * HID;
    float acc = b_fc[o];
#pragma unroll 8
    for (int k = 0; k < HID; ++k) acc += hrow[k] * wrow[k];
    out[idx] = acc;
}

// ---------------------------------------------------------------------------
extern "C" void kernel_launch(void* const* d_in, const int* in_sizes, int n_in,
                              void* d_out, int out_size, void* d_ws, size_t ws_size,
                              hipStream_t stream) {
    const float* x    = (const float*)d_in[0];  // [B, T, I]
    const float* w_ih = (const float*)d_in[1];  // [4H, I]
    const float* w_hh = (const float*)d_in[2];  // [4H, H]
    const float* b_ih = (const float*)d_in[3];  // [4H]
    const float* b_hh = (const float*)d_in[4];  // [4H]
    const float* w_fc = (const float*)d_in[5];  // [OUT, H]
    const float* b_fc = (const float*)d_in[6];  // [OUT]
    float* out = (float*)d_out;                 // [T, OUT]

    // Only batch element B-1 is observable in the reference output.
    const float* x255 = x + (size_t)(BATCH - 1) * T_STEPS * IN_DIM;

    float* hs = (float*)d_ws;                                  // 4096*128 f32 = 2 MB
    float* gx2 = hs + (size_t)T_STEPS * HID;                   // 4096*512 f32 = 8 MB (unit-major)
    const size_t need_full = (size_t)(T_STEPS * HID + T_STEPS * GATES) * sizeof(float);

    if (ws_size >= need_full) {
        k_inproj<<<T_STEPS, GATES, 0, stream>>>(x255, w_ih, b_ih, b_hh, gx2);
        k_scan_mfma<<<1, GATES, 0, stream>>>(gx2, w_hh, hs);
    } else {
        k_scan_valu<<<1, GATES, 0, stream>>>(w_hh, hs, x255, w_ih, b_ih, b_hh);
    }

    const int n = T_STEPS * OUT_DIM;
    k_fc<<<(n + 255) / 256, 256, 0, stream>>>(hs, w_fc, b_fc, out);
}

// Round 13
// 2164.833 us; speedup vs baseline: 1.2153x; 1.0650x over previous
//
#include <hip/hip_runtime.h>
#include <hip/hip_bf16.h>
#include <math.h>

// Problem constants
#define BATCH   256
#define T_STEPS 4096
#define IN_DIM  28
#define HID     128
#define GATES   512   // 4*HID
#define OUT_DIM 10

#define HPAD    16                    // ushort pad: buf/par regions hit different banks
#define PARSTRIDE (HID + HPAD)        // ushorts between par=0 and par=1 regions
#define BUFSTRIDE (2 * PARSTRIDE)     // ushorts between buf 0 and buf 1

typedef short bf16x8 __attribute__((ext_vector_type(8)));  // 8 bf16 in 4 VGPRs
typedef float f32x4  __attribute__((ext_vector_type(4)));

#define SGB __builtin_amdgcn_sched_group_barrier
// LLVM SchedGroupMask: VALU=0x2, MFMA=0x8, DS_READ=0x100

// LDS-only barrier (R13): __syncthreads() emits s_waitcnt vmcnt(0) expcnt(0)
// lgkmcnt(0) + s_barrier — draining the hs global STORE (issued in the tail,
// ~100-300cy ack latency) and the gx prefetch every step. The barrier only
// needs LDS ordering: lgkmcnt(0) commits this wave's ds_writes, s_barrier
// orders waves. hs needs no intra-kernel ordering (read by k_fc, a later
// dispatch); gx's vmcnt wait is inserted by the backend at first use.
// sched_barrier(0) fences (rule #18: compiler hoists past inline-asm waitcnt).
#define BAR_LDS()                                                              \
    do {                                                                       \
        __builtin_amdgcn_sched_barrier(0);                                     \
        asm volatile("s_waitcnt lgkmcnt(0)" ::: "memory");                     \
        __builtin_amdgcn_s_barrier();                                          \
        __builtin_amdgcn_sched_barrier(0);                                     \
    } while (0)

__device__ __forceinline__ float frcp_fast(float x) {
    return __builtin_amdgcn_rcpf(x);
}

__device__ __forceinline__ unsigned short f2bf(float f) {
    __hip_bfloat16 h = __float2bfloat16(f);   // RNE
    return __builtin_bit_cast(unsigned short, h);
}
__device__ __forceinline__ float bf2f(unsigned short u) {
    return __bfloat162float(__builtin_bit_cast(__hip_bfloat16, u));
}

__device__ __forceinline__ float sigm(float x) {
    float e = __builtin_exp2f(x * -1.44269504f);
    return frcp_fast(1.0f + e);
}
__device__ __forceinline__ float tanh_fast(float x) {
    // tanh(x) = 1 - 2/(1+e^{2x}) — exact at both infinities
    float e = __builtin_exp2f(x * 2.88539008f);
    return 1.0f - 2.0f * frcp_fast(1.0f + e);
}

// ---------------------------------------------------------------------------
// Kernel 1: input projection for batch element 255, UNIT-MAJOR output:
// gx2[t, u, gt] = dot(x255[t,:], w_ih[gt*128+u,:]) + b_ih[..] + b_hh[..]
// ---------------------------------------------------------------------------
__global__ __launch_bounds__(GATES) void k_inproj(const float* __restrict__ x255,
                                                  const float* __restrict__ w_ih,
                                                  const float* __restrict__ b_ih,
                                                  const float* __restrict__ b_hh,
                                                  float* __restrict__ gx2) {
    const int t = blockIdx.x;
    const int g = threadIdx.x;          // gate row 0..511 (i|f|g|o blocks of 128)
    const int unit = g & (HID - 1);
    const int quad = g >> 7;
    __shared__ float xs[IN_DIM];
    if (g < IN_DIM) xs[g] = x255[t * IN_DIM + g];
    __syncthreads();
    float acc = b_ih[g] + b_hh[g];
    const float* __restrict__ wr = w_ih + g * IN_DIM;
#pragma unroll
    for (int k = 0; k < IN_DIM; ++k) acc += wr[k] * xs[k];
    gx2[t * GATES + unit * 4 + quad] = acc;
}

// ---------------------------------------------------------------------------
// Kernel 2 (main): MFMA LSTM scan — 512 threads (8 waves), unit-major,
// operand-swapped (R7-verified): A = h (EVEN rows h_hi, ODD rows h_lo),
// B = W_hh (col n = unit). Lane: col cidx = its unit; reg0 = hi-part,
// reg1 = lo-part -> pre = a[0]+a[1]+gx, static regs.
//
// R13 = R9/R12 (best measured, 2306-2308us, reproduced twice) + BAR_LDS:
// the ONLY change is replacing __syncthreads() (full vmcnt/expcnt/lgkmcnt
// drain) with an LDS-only barrier, so the hs store-ack and gx prefetch
// latency run concurrent with the next step instead of being serially
// drained every step.
// Floor arithmetic (R5-R12): 128 MFMA/step / 4 SIMD x ~16.5cy = ~530cy
// issue floor (M-redundancy structural: B can't vary with M, hi/lo fills
// 2/16 rows; MX-fp8 K=128 issue cost ~1.8x for 2x count = no gain) +
// ds_read/dep-MFMA/activation-chain/barrier latency. Six scheduling
// attacks (R6-R11) all landed within ±5% of this structure or regressed.
// ---------------------------------------------------------------------------
__global__ __attribute__((amdgpu_flat_work_group_size(512, 512),
                          amdgpu_waves_per_eu(2, 2)))
void k_scan_mfma(const float* __restrict__ gx2,
                 const float* __restrict__ w_hh,
                 float* __restrict__ hs) {
    const int tid   = threadIdx.x;
    const int w     = tid >> 6;         // wave 0..7
    const int l     = tid & 63;         // lane 0..63
    const int q     = l >> 4;           // k-group / D row-group 0..3
    const int cidx  = l & 15;           // D column = unit within wave
    const int par   = cidx & 1;         // A-row parity: 0 -> h_hi, 1 -> h_lo
    const int ubase = w * 16;
    const int u     = ubase + cidx;     // unit this lane finalizes

    __shared__ __align__(16) unsigned short hb[2 * BUFSTRIDE];

    // ---- one-time: B-frags wb_[gate_type][kt] (64 VGPRs) ----
    // lane l holds B[k = kt*32 + q*8 + j][col = cidx] = W_hh[gt*128+u][k]
    bf16x8 wb_[4][4];
#pragma unroll
    for (int gt = 0; gt < 4; ++gt) {
        const int row = gt * HID + u;
        const float* __restrict__ wr = w_hh + row * HID;
#pragma unroll
        for (int kt = 0; kt < 4; ++kt) {
            const int k0 = kt * 32 + q * 8;
            bf16x8 v;
#pragma unroll
            for (int j = 0; j < 8; ++j) v[j] = (short)f2bf(wr[k0 + j]);
            wb_[gt][kt] = v;
        }
    }

    // zero both buffers (both parities)
    if (tid < HID) {
        hb[0 * BUFSTRIDE + 0 * PARSTRIDE + tid] = 0;
        hb[0 * BUFSTRIDE + 1 * PARSTRIDE + tid] = 0;
        hb[1 * BUFSTRIDE + 0 * PARSTRIDE + tid] = 0;
        hb[1 * BUFSTRIDE + 1 * PARSTRIDE + tid] = 0;
    }
    float c = 0.0f;                     // cell state (4x replicated per unit)
    const unsigned short* __restrict__ hq = &hb[par * PARSTRIDE + q * 8]; // A-frag base
    unsigned short* __restrict__ wpt = &hb[u];                            // writer base
    const f32x4 ZQ = {0.f, 0.f, 0.f, 0.f};   // persistent zero C-operand

    float4 gnext = *reinterpret_cast<const float4*>(gx2 + u * 4);  // t=0
    __syncthreads();

#define MF(A, G, K, C_) __builtin_amdgcn_mfma_f32_16x16x32_bf16((A), wb_[G][K], (C_), 0, 0, 0)

#define LSTM_STEP(T, RB, WB)                                                   \
    {                                                                          \
        float4 gcur = gnext;                                                   \
        if ((T) + 1 < T_STEPS)                                                 \
            gnext = *reinterpret_cast<const float4*>(gx2 + ((T) + 1) * GATES + u * 4); \
        bf16x8 af0 = *reinterpret_cast<const bf16x8*>(hq + (RB) * BUFSTRIDE + 0 * 32); \
        bf16x8 af1 = *reinterpret_cast<const bf16x8*>(hq + (RB) * BUFSTRIDE + 1 * 32); \
        bf16x8 af2 = *reinterpret_cast<const bf16x8*>(hq + (RB) * BUFSTRIDE + 2 * 32); \
        bf16x8 af3 = *reinterpret_cast<const bf16x8*>(hq + (RB) * BUFSTRIDE + 3 * 32); \
        /* g-gate chain first (its tanh is the longest activation) */          \
        f32x4 a2 = MF(af0, 2, 0, ZQ);                                          \
        a2 = MF(af1, 2, 1, a2);                                                \
        a2 = MF(af2, 2, 2, a2);                                                \
        a2 = MF(af3, 2, 3, a2);                                                \
        /* o-chain, g-activation threaded between */                           \
        f32x4 a3 = MF(af0, 3, 0, ZQ);                                          \
        float p2 = (a2[0] + a2[1]) + gcur.z;                                   \
        a3 = MF(af1, 3, 1, a3);                                                \
        float eg = __builtin_exp2f(p2 * 2.88539008f);                          \
        a3 = MF(af2, 3, 2, a3);                                                \
        float dg = 1.0f + eg;                                                  \
        a3 = MF(af3, 3, 3, a3);                                                \
        float gv = __builtin_fmaf(-2.0f, frcp_fast(dg), 1.0f);                 \
        /* i-chain, o-activation threaded between */                           \
        f32x4 a0 = MF(af0, 0, 0, ZQ);                                          \
        float p3 = (a3[0] + a3[1]) + gcur.w;                                   \
        a0 = MF(af1, 0, 1, a0);                                                \
        float eo = __builtin_exp2f(p3 * -1.44269504f);                         \
        a0 = MF(af2, 0, 2, a0);                                                \
        float dosum = 1.0f + eo;                                               \
        a0 = MF(af3, 0, 3, a0);                                                \
        float ov = frcp_fast(dosum);                                           \
        /* f-chain, i-activation threaded between */                           \
        f32x4 a1 = MF(af0, 1, 0, ZQ);                                          \
        float p0 = (a0[0] + a0[1]) + gcur.x;                                   \
        a1 = MF(af1, 1, 1, a1);                                                \
        float ei = __builtin_exp2f(p0 * -1.44269504f);                         \
        a1 = MF(af2, 1, 2, a1);                                                \
        float di = 1.0f + ei;                                                  \
        a1 = MF(af3, 1, 3, a1);                                                \
        float iv = frcp_fast(di);                                              \
        /* tail */                                                             \
        float p1 = (a1[0] + a1[1]) + gcur.y;                                   \
        float ef = __builtin_exp2f(p1 * -1.44269504f);                         \
        float fv = frcp_fast(1.0f + ef);                                       \
        float ig = iv * gv;                                                    \
        c = __builtin_fmaf(fv, c, ig);                                         \
        float ec = __builtin_exp2f(c * 2.88539008f);                           \
        float th = __builtin_fmaf(-2.0f, frcp_fast(1.0f + ec), 1.0f);          \
        float h = ov * th;                                                     \
        unsigned short hi = f2bf(h);                                           \
        if (q == 0) wpt[(WB) * BUFSTRIDE] = hi;                                \
        if (q == 1) wpt[(WB) * BUFSTRIDE + PARSTRIDE] = f2bf(h - bf2f(hi));    \
        if (q == 2) hs[(T) * HID + u] = h;                                     \
        /* pin the interleave: reads, g-burst, then MFMA/VALU alternation */   \
        SGB(0x100, 4, 0);                                                      \
        SGB(0x008, 4, 0);                                                      \
        SGB(0x008, 1, 0); SGB(0x002, 2, 0);                                    \
        SGB(0x008, 1, 0); SGB(0x002, 2, 0);                                    \
        SGB(0x008, 1, 0); SGB(0x002, 2, 0);                                    \
        SGB(0x008, 1, 0); SGB(0x002, 2, 0);                                    \
        SGB(0x008, 1, 0); SGB(0x002, 2, 0);                                    \
        SGB(0x008, 1, 0); SGB(0x002, 2, 0);                                    \
        SGB(0x008, 1, 0); SGB(0x002, 2, 0);                                    \
        SGB(0x008, 1, 0); SGB(0x002, 2, 0);                                    \
        SGB(0x008, 1, 0); SGB(0x002, 2, 0);                                    \
        SGB(0x008, 1, 0); SGB(0x002, 2, 0);                                    \
        SGB(0x008, 1, 0); SGB(0x002, 2, 0);                                    \
        SGB(0x008, 1, 0); SGB(0x002, 2, 0);                                    \
        BAR_LDS();                                                             \
    }

    for (int t = 0; t < T_STEPS; t += 2) {
        LSTM_STEP(t, 1, 0);       // even step: read buf1 (zeroed at t=0), write buf0
        LSTM_STEP(t + 1, 0, 1);   // odd step: read buf0, write buf1
    }
#undef LSTM_STEP
#undef MF
}

// ---------------------------------------------------------------------------
// Fallback scan (fused input projection, f32 VALU) — only if d_ws too small.
// ---------------------------------------------------------------------------
__global__ __launch_bounds__(GATES) void k_scan_valu(const float* __restrict__ w_hh,
                                                     float* __restrict__ hs,
                                                     const float* __restrict__ x255,
                                                     const float* __restrict__ w_ih,
                                                     const float* __restrict__ b_ih,
                                                     const float* __restrict__ b_hh) {
    const int g    = threadIdx.x;
    const int quad = g >> 7;

    __shared__ float h_sh[HID];
    __shared__ float act_sh[GATES];
    __shared__ float xs[IN_DIM];

    float4 wv[HID / 4];
    const float4* __restrict__ wrow = reinterpret_cast<const float4*>(w_hh + g * HID);
#pragma unroll
    for (int k = 0; k < HID / 4; ++k) wv[k] = wrow[k];

    float bsum = b_ih[g] + b_hh[g];
    float wih[IN_DIM];
#pragma unroll
    for (int k = 0; k < IN_DIM; ++k) wih[k] = w_ih[g * IN_DIM + k];

    if (g < HID) h_sh[g] = 0.0f;
    float c = 0.0f;
    __syncthreads();

    for (int t = 0; t < T_STEPS; ++t) {
        __syncthreads();
        if (g < IN_DIM) xs[g] = x255[t * IN_DIM + g];
        __syncthreads();
        float a0 = bsum, a1 = 0.0f, a2 = 0.0f, a3 = 0.0f;
#pragma unroll
        for (int k = 0; k < IN_DIM; ++k) a0 += wih[k] * xs[k];

        const float4* __restrict__ h4 = reinterpret_cast<const float4*>(h_sh);
#pragma unroll
        for (int k = 0; k < HID / 4; ++k) {
            float4 hv = h4[k];
            a0 += wv[k].x * hv.x;
            a1 += wv[k].y * hv.y;
            a2 += wv[k].z * hv.z;
            a3 += wv[k].w * hv.w;
        }
        float pre = (a0 + a1) + (a2 + a3);
        float a = (quad == 2) ? tanh_fast(pre) : sigm(pre);
        act_sh[g] = a;
        __syncthreads();

        if (g < HID) {
            float iv = act_sh[g];
            float fv = act_sh[HID + g];
            float gv = act_sh[2 * HID + g];
            float ov = act_sh[3 * HID + g];
            c = fv * c + iv * gv;
            float h = ov * tanh_fast(c);
            h_sh[g] = h;
            hs[t * HID + g] = h;
        }
        __syncthreads();
    }
}

// ---------------------------------------------------------------------------
// Kernel 3: final FC — out[t, o] = dot(hs[t, :], w_fc[o, :]) + b_fc[o]
// ---------------------------------------------------------------------------
__global__ __launch_bounds__(256) void k_fc(const float* __restrict__ hs,
                                            const float* __restrict__ w_fc,
                                            const float* __restrict__ b_fc,
                                            float* __restrict__ out) {
    const int idx = blockIdx.x * blockDim.x + threadIdx.x;
    if (idx >= T_STEPS * OUT_DIM) return;
    const int t = idx / OUT_DIM;
    const int o = idx - t * OUT_DIM;
    const float* __restrict__ hrow = hs + t * HID;
    const float* __restrict__ wrow = w_fc + o * HID;
    float acc = b_fc[o];
#pragma unroll 8
    for (int k = 0; k < HID; ++k) acc += hrow[k] * wrow[k];
    out[idx] = acc;
}

// ---------------------------------------------------------------------------
extern "C" void kernel_launch(void* const* d_in, const int* in_sizes, int n_in,
                              void* d_out, int out_size, void* d_ws, size_t ws_size,
                              hipStream_t stream) {
    const float* x    = (const float*)d_in[0];  // [B, T, I]
    const float* w_ih = (const float*)d_in[1];  // [4H, I]
    const float* w_hh = (const float*)d_in[2];  // [4H, H]
    const float* b_ih = (const float*)d_in[3];  // [4H]
    const float* b_hh = (const float*)d_in[4];  // [4H]
    const float* w_fc = (const float*)d_in[5];  // [OUT, H]
    const float* b_fc = (const float*)d_in[6];  // [OUT]
    float* out = (float*)d_out;                 // [T, OUT]

    // Only batch element B-1 is observable in the reference output.
    const float* x255 = x + (size_t)(BATCH - 1) * T_STEPS * IN_DIM;

    float* hs = (float*)d_ws;                                  // 4096*128 f32 = 2 MB
    float* gx2 = hs + (size_t)T_STEPS * HID;                   // 4096*512 f32 = 8 MB (unit-major)
    const size_t need_full = (size_t)(T_STEPS * HID + T_STEPS * GATES) * sizeof(float);

    if (ws_size >= need_full) {
        k_inproj<<<T_STEPS, GATES, 0, stream>>>(x255, w_ih, b_ih, b_hh, gx2);
        k_scan_mfma<<<1, GATES, 0, stream>>>(gx2, w_hh, hs);
    } else {
        k_scan_valu<<<1, GATES, 0, stream>>>(w_hh, hs, x255, w_ih, b_ih, b_hh);
    }

    const int n = T_STEPS * OUT_DIM;
    k_fc<<<(n + 255) / 256, 256, 0, stream>>>(hs, w_fc, b_fc, out);
}